// Round 6
// baseline (2559.873 us; speedup 1.0000x reference)
//
#include <hip/hip_runtime.h>
#include <stdint.h>

// Problem constants (fixed by setup_inputs)
#define Bn 256
#define Hn 768
#define Tn 128
#define KS 24      // Hn/32 ksteps
#define CBn 48     // col-blocks (j-tiles of 16 hidden units x 3 gates)
#define RGn 4      // row-groups of 64 batch rows
#define NTHR 256   // 4 waves; wave w owns m-tile w (16 rows), all gates, full K
#define NBLK 192   // CBn * RGn
#define SMEM_BYTES 147456  // W slice hi+lo in LDS (dynamic)

typedef __attribute__((ext_vector_type(8))) short short8;   // 8 bf16
typedef __attribute__((ext_vector_type(4))) float floatx4;  // mfma C/D

static __device__ __forceinline__ unsigned short f2bf(float f) {
  unsigned int x = __float_as_uint(f);
  x += 0x7fffu + ((x >> 16) & 1u);
  return (unsigned short)(x >> 16);
}
static __device__ __forceinline__ float bf2f(unsigned short u) {
  return __uint_as_float(((unsigned int)u) << 16);
}

// Device-coherent 16B load as two agent-scope relaxed atomic b64 loads.
// Same instruction class as the (empirically cross-XCD-visible) flag polls
// of r2-r4: reads at the L3 coherence point, bypassing stale L1/L2 -- no
// per-step cache invalidate needed anywhere.
static __device__ __forceinline__ short8 ld_coh16(const unsigned short* p) {
  union { unsigned long long u[2]; short8 v; } r;
  const unsigned long long* q = (const unsigned long long*)p;
  r.u[0] = __hip_atomic_load(q,     __ATOMIC_RELAXED, __HIP_MEMORY_SCOPE_AGENT);
  r.u[1] = __hip_atomic_load(q + 1, __ATOMIC_RELAXED, __HIP_MEMORY_SCOPE_AGENT);
  return r.v;
}
static __device__ __forceinline__ unsigned int ld_coh4(const unsigned short* p) {
  return __hip_atomic_load((const unsigned int*)p, __ATOMIC_RELAXED,
                           __HIP_MEMORY_SCOPE_AGENT);
}

// ---------------------------------------------------------------------------
// Swizzle W_hh (2304x768 fp32 row-major) into slice-contiguous B-fragment
// order, bf16 hi/lo interleaved per chunk (unchanged).
// ---------------------------------------------------------------------------
__global__ void swz_w(const float* __restrict__ W,
                      unsigned short* __restrict__ wsw) {
  int i = blockIdx.x * blockDim.x + threadIdx.x;
  if (i >= 2304 * (Hn / 8)) return;
  int n  = i / (Hn / 8);
  int k0 = (i % (Hn / 8)) * 8;
  int g = n / Hn, jj = n % Hn;
  int cb = jj >> 4, l15 = jj & 15;
  int ks = k0 >> 5, k8 = (k0 >> 3) & 3;
  int lane = l15 + 16 * k8;
  unsigned short* slice = wsw + (size_t)cb * 73728;
  size_t offh = ((size_t)((g * KS + ks) * 2 + 0)) * 512 + (size_t)lane * 8;
  size_t offl = ((size_t)((g * KS + ks) * 2 + 1)) * 512 + (size_t)lane * 8;
  const float* src = W + (size_t)n * Hn + k0;
  short8 h8, l8;
#pragma unroll
  for (int q = 0; q < 8; ++q) {
    float w = src[q];
    unsigned short hb = f2bf(w);
    h8[q] = (short)hb;
    l8[q] = (short)f2bf(w - bf2f(hb));
  }
  *(short8*)(slice + offh) = h8;
  *(short8*)(slice + offl) = l8;
}

// ---------------------------------------------------------------------------
// Init: h0 planes (bf16 hi/lo) from context; zero ddot; zero barrier flags.
// hbase layout: [hhi0 | hlo0 | hhi1 | hlo1], each Bn*Hn elements.
// ---------------------------------------------------------------------------
__global__ void init_h(const float* __restrict__ ctx,
                       unsigned short* __restrict__ hbase,
                       float* __restrict__ ddot, int* __restrict__ flags) {
  int i = blockIdx.x * blockDim.x + threadIdx.x;
  if (i < Bn * Hn) {
    float c = ctx[i];
    unsigned short hb = f2bf(c);
    hbase[i] = hb;                            // hhi0
    hbase[Bn * Hn + i] = f2bf(c - bf2f(hb));  // hlo0
  }
  if (i < Tn * Bn) ddot[i] = 0.f;
  if (i < RGn * 128) flags[i] = 0;
}

// ---------------------------------------------------------------------------
// PERSISTENT cooperative kernel -- FENCELESS coherence (safe codegen).
//  r4 lesson: the per-step fence(acquire,agent) flash-invalidates ALL L1+L2
//  on every XCD every step -> the whole kernel runs cache-cold; that, not
//  barrier detection, is the dominant residual cost (3 barrier rewrites
//  moved only ~5us total).
//  r5 lesson: hand-rolled asm sc0/sc1 loads hung the container; same idea is
//  now expressed with __hip_atomic_load (RELAXED, AGENT) -- the instruction
//  class whose cross-XCD visibility r2-r4's flag polls already proved on HW.
//  Scheme:
//   - producer h stores: __hip_atomic_store agent (sc1, write-through to L3)
//   - consumer h reads (A frags + h_old): __hip_atomic_load agent (read at
//     the L3 coherence point; stale per-XCD L2 never consulted)
//   - NO fence anywhere; L2 stays warm for LDS-staging/bias/flags lines.
//  Ordering: h stores drained (s_waitcnt vmcnt(0)) -> block sync -> flag
//  store -> leader polls arrivals -> done word -> followers pass -> block
//  sync -> next step's atomic loads (control-dependent on the poll).
//  WAR safety: double-buffered h + monotone epochs, same induction as r1-r4.
//  Barrier: two-level per-rg (r4-proven): 48 parallel arrival-flag stores,
//  leader (cb==0) polls them, publishes one done word, 47 followers poll
//  that single broadcast word (64 lanes on one address).
// ---------------------------------------------------------------------------
__global__ __launch_bounds__(NTHR, 1) void gru_all(
    const unsigned short* __restrict__ wsw,
    unsigned short* hbase,
    const float* __restrict__ bias_ih, const float* __restrict__ bias_hh,
    const float* __restrict__ fc_w, float* __restrict__ ddot,
    int* flags) {
  extern __shared__ char smem[];
  unsigned short* lds_w = (unsigned short*)smem;  // 144 chunks x 1 KiB

  const int bid = blockIdx.x;              // 0..191
  const int rg = (bid & 7) >> 1;           // XCD pair -> one row-group
  const int cb = ((bid >> 3) << 1) | (bid & 1);
  const int tid = threadIdx.x;
  const int lane = tid & 63;
  const int wave = tid >> 6;
  const int ln15 = lane & 15, quad = lane >> 4;
  const bool leader = (cb == 0);

  // ---- async W staging, ONCE ----
  const unsigned short* wsrc = wsw + (size_t)cb * 73728;
  for (int i = 0; i < 36; ++i) {
    const int c = wave * 36 + i;
    __builtin_amdgcn_global_load_lds(
        (const __attribute__((address_space(1))) unsigned int*)(wsrc + (size_t)c * 512 + lane * 8),
        (__attribute__((address_space(3))) unsigned int*)(lds_w + (size_t)c * 512),
        16, 0, 0);
  }

  // ---- per-lane constants ----
  const int j = cb * 16 + ln15;
  const float bir = bias_ih[j], biz = bias_ih[Hn + j], bin = bias_ih[2 * Hn + j];
  const float bhr = bias_hh[j], bhz = bias_hh[Hn + j], bhn = bias_hh[2 * Hn + j];
  const float fw = fc_w[j];
  const int mrow0 = rg * 64 + wave * 16;  // wave's 16 rows
  const size_t N = (size_t)Bn * Hn;
  const bool evenlane = ((ln15 & 1) == 0);
  const bool oddj = (ln15 & 1);
  int* const myflag = flags + rg * 128 + cb;
  int* const pollp  = flags + rg * 128 + ((lane < CBn) ? lane : (CBn - 1));
  int* const donep  = flags + rg * 128 + 64;  // own cache line (bytes 256..)

  __syncthreads();  // drains vmcnt(0): W staging complete; W read-only after

  float fcv[4];

  for (int t = 0; t < Tn; ++t) {
    const unsigned short* hhi_in = hbase + (size_t)(t & 1) * (2 * N);
    const unsigned short* hlo_in = hhi_in + N;
    unsigned short* hhi_out = hbase + (size_t)((t & 1) ^ 1) * (2 * N);
    unsigned short* hlo_out = hhi_out + N;

    const unsigned short* Ah_base = hhi_in + (size_t)(mrow0 + ln15) * Hn + quad * 8;
    const unsigned short* Al_base = hlo_in + (size_t)(mrow0 + ln15) * Hn + quad * 8;

    // ---- device-coherent A prefetch (reads at L3, no invalidate needed) ----
    short8 Abh[6][4], Abl[6][4];
#pragma unroll
    for (int c = 0; c < 6; ++c) {
#pragma unroll
      for (int q = 0; q < 4; ++q) {
        Abh[c][q] = ld_coh16(Ah_base + (c * 4 + q) * 32);
        Abl[c][q] = ld_coh16(Al_base + (c * 4 + q) * 32);
      }
    }
    // h_old as packed dwords (the pair the producer's dword store wrote)
    unsigned int hd[4], ldw[4];
#pragma unroll
    for (int i = 0; i < 4; ++i) {
      size_t ridx = (size_t)(mrow0 + quad * 4 + i) * Hn + (size_t)(j & ~1);
      hd[i]  = ld_coh4(hhi_in + ridx);
      ldw[i] = ld_coh4(hlo_in + ridx);
    }

    floatx4 acc[3];
#pragma unroll
    for (int g = 0; g < 3; ++g) acc[g] = (floatx4){0.f, 0.f, 0.f, 0.f};

#pragma unroll
    for (int c = 0; c < 6; ++c) {
#pragma unroll
      for (int kk = 0; kk < 4; ++kk) {
        const int ks = c * 4 + kk;
#pragma unroll
        for (int g = 0; g < 3; ++g) {
          const int cbase = ((g * KS + ks) * 2) * 512 + lane * 8;
          short8 Bh = *(const short8*)(lds_w + cbase);
          short8 Bl = *(const short8*)(lds_w + cbase + 512);
          acc[g] = __builtin_amdgcn_mfma_f32_16x16x32_bf16(Abh[c][kk], Bh, acc[g], 0, 0, 0);
          acc[g] = __builtin_amdgcn_mfma_f32_16x16x32_bf16(Abl[c][kk], Bh, acc[g], 0, 0, 0);
          acc[g] = __builtin_amdgcn_mfma_f32_16x16x32_bf16(Abh[c][kk], Bl, acc[g], 0, 0, 0);
        }
      }
    }

    // ---- epilogue: gates + h_new + fc partial (identical numerics) ----
    unsigned int ph[4], pl[4];
#pragma unroll
    for (int i = 0; i < 4; ++i) {
      float gr = bir + bhr + acc[0][i];
      float gz = biz + bhz + acc[1][i];
      float rr = 1.f / (1.f + __expf(-gr));
      float zz = 1.f / (1.f + __expf(-gz));
      float gn = bin + rr * (acc[2][i] + bhn);
      float nn = 1.f - 2.f / (1.f + __expf(2.f * gn));  // tanh
      unsigned short uh = oddj ? (unsigned short)(hd[i] >> 16)
                               : (unsigned short)(hd[i] & 0xffffu);
      unsigned short ul = oddj ? (unsigned short)(ldw[i] >> 16)
                               : (unsigned short)(ldw[i] & 0xffffu);
      float hold = bf2f(uh) + bf2f(ul);
      float hn = (1.f - zz) * nn + zz * hold;
      unsigned short hb = f2bf(hn);
      ph[i] = (unsigned int)hb;
      pl[i] = (unsigned int)f2bf(hn - bf2f(hb));
      fcv[i] = hn * fw;
    }
    // pack adjacent-j pairs (lane^1 holds j^1; same rows) -> dword sc1 stores
#pragma unroll
    for (int i = 0; i < 4; ++i) {
      unsigned int oh = (unsigned int)__shfl_xor((int)ph[i], 1);
      unsigned int ol = (unsigned int)__shfl_xor((int)pl[i], 1);
      if (evenlane) {
        size_t idx = (size_t)(mrow0 + quad * 4 + i) * Hn + j;  // j even
        __hip_atomic_store((unsigned int*)(hhi_out + idx), ph[i] | (oh << 16),
                           __ATOMIC_RELAXED, __HIP_MEMORY_SCOPE_AGENT);
        __hip_atomic_store((unsigned int*)(hlo_out + idx), pl[i] | (ol << 16),
                           __ATOMIC_RELAXED, __HIP_MEMORY_SCOPE_AGENT);
      }
    }
    // fc partial reduce in-register
#pragma unroll
    for (int i = 0; i < 4; ++i) {
      fcv[i] += __shfl_xor(fcv[i], 1);
      fcv[i] += __shfl_xor(fcv[i], 2);
      fcv[i] += __shfl_xor(fcv[i], 4);
      fcv[i] += __shfl_xor(fcv[i], 8);
    }

    // ---- two-level per-rg barrier, NO acquire fence ----
    if (t < Tn - 1) {
      asm volatile("s_waitcnt vmcnt(0)" ::: "memory");  // h stores acked at L3
      __syncthreads();                                  // whole block drained
      if (tid == 0)
        __hip_atomic_store(myflag, t + 1, __ATOMIC_RELAXED,
                           __HIP_MEMORY_SCOPE_AGENT);   // own slot: no RMW
      // ddot atomics fire into the barrier shadow (consumed only by post_k)
      if (ln15 == 0) {
#pragma unroll
        for (int i = 0; i < 4; ++i)
          atomicAdd(&ddot[(size_t)t * Bn + mrow0 + quad * 4 + i], fcv[i]);
      }
      if (wave == 0) {
        if (leader) {
          for (;;) {
            int v = __hip_atomic_load(pollp, __ATOMIC_RELAXED,
                                      __HIP_MEMORY_SCOPE_AGENT);
            if (__all(v >= t + 1)) break;
            __builtin_amdgcn_s_sleep(1);
          }
          if (lane == 0)
            __hip_atomic_store(donep, t + 1, __ATOMIC_RELAXED,
                               __HIP_MEMORY_SCOPE_AGENT);
        } else {
          for (;;) {
            int v = __hip_atomic_load(donep, __ATOMIC_RELAXED,
                                      __HIP_MEMORY_SCOPE_AGENT);
            if (v >= t + 1) break;
            __builtin_amdgcn_s_sleep(2);
          }
        }
      }
      __syncthreads();  // all waves pass together; compiler memory barrier
    } else {
      if (ln15 == 0) {
#pragma unroll
        for (int i = 0; i < 4; ++i)
          atomicAdd(&ddot[(size_t)t * Bn + mrow0 + quad * 4 + i], fcv[i]);
      }
    }
  }
}

// ---------------------------------------------------------------------------
// Fallback: proven one-step-per-dispatch kernel (used only if cooperative
// launch is rejected). Unchanged from the verified 1944us version.
// ---------------------------------------------------------------------------
__global__ __launch_bounds__(NTHR) void gru_step(
    const unsigned short* __restrict__ wsw,
    const unsigned short* __restrict__ hhi_in,
    const unsigned short* __restrict__ hlo_in,
    unsigned short* __restrict__ hhi_out,
    unsigned short* __restrict__ hlo_out,
    const float* __restrict__ bias_ih, const float* __restrict__ bias_hh,
    const float* __restrict__ fc_w, float* __restrict__ ddot_t) {
  extern __shared__ char smem[];
  unsigned short* lds_w = (unsigned short*)smem;

  const int cb = blockIdx.x;
  const int rg = blockIdx.y;
  const int tid = threadIdx.x;
  const int lane = tid & 63;
  const int wave = tid >> 6;
  const int ln15 = lane & 15, quad = lane >> 4;
  const int j0 = cb * 16;

  const unsigned short* wsrc = wsw + (size_t)cb * 73728;
  for (int i = 0; i < 36; ++i) {
    const int c = wave * 36 + i;
    __builtin_amdgcn_global_load_lds(
        (const __attribute__((address_space(1))) unsigned int*)(wsrc + (size_t)c * 512 + lane * 8),
        (__attribute__((address_space(3))) unsigned int*)(lds_w + (size_t)c * 512),
        16, 0, 0);
  }

  const int j = j0 + ln15;
  const float bir = bias_ih[j], biz = bias_ih[Hn + j], bin = bias_ih[2 * Hn + j];
  const float bhr = bias_hh[j], bhz = bias_hh[Hn + j], bhn = bias_hh[2 * Hn + j];
  const float fw = fc_w[j];
  const int mrow0 = rg * 64 + wave * 16;

  unsigned short hoh[4], hol[4];
#pragma unroll
  for (int i = 0; i < 4; ++i) {
    size_t idx = (size_t)(mrow0 + quad * 4 + i) * Hn + j;
    hoh[i] = hhi_in[idx];
    hol[i] = hlo_in[idx];
  }

  const unsigned short* Ah_base = hhi_in + (size_t)(mrow0 + ln15) * Hn + quad * 8;
  const unsigned short* Al_base = hlo_in + (size_t)(mrow0 + ln15) * Hn + quad * 8;

  floatx4 acc[3];
#pragma unroll
  for (int g = 0; g < 3; ++g) acc[g] = (floatx4){0.f, 0.f, 0.f, 0.f};

  short8 Abh[2][4], Abl[2][4];
#pragma unroll
  for (int q = 0; q < 4; ++q) {
    Abh[0][q] = *(const short8*)(Ah_base + q * 32);
    Abl[0][q] = *(const short8*)(Al_base + q * 32);
  }

  __syncthreads();

#pragma unroll
  for (int c = 0; c < 6; ++c) {
    const int cur = c & 1, nxt = cur ^ 1;
    if (c < 5) {
#pragma unroll
      for (int q = 0; q < 4; ++q) {
        Abh[nxt][q] = *(const short8*)(Ah_base + ((c + 1) * 4 + q) * 32);
        Abl[nxt][q] = *(const short8*)(Al_base + ((c + 1) * 4 + q) * 32);
      }
    }
#pragma unroll
    for (int kk = 0; kk < 4; ++kk) {
      const int ks = c * 4 + kk;
#pragma unroll
      for (int g = 0; g < 3; ++g) {
        const int cbase = ((g * KS + ks) * 2) * 512 + lane * 8;
        short8 Bh = *(const short8*)(lds_w + cbase);
        short8 Bl = *(const short8*)(lds_w + cbase + 512);
        acc[g] = __builtin_amdgcn_mfma_f32_16x16x32_bf16(Abh[cur][kk], Bh, acc[g], 0, 0, 0);
        acc[g] = __builtin_amdgcn_mfma_f32_16x16x32_bf16(Abl[cur][kk], Bh, acc[g], 0, 0, 0);
        acc[g] = __builtin_amdgcn_mfma_f32_16x16x32_bf16(Abh[cur][kk], Bl, acc[g], 0, 0, 0);
      }
    }
  }

  float fcv[4];
#pragma unroll
  for (int i = 0; i < 4; ++i) {
    const int r = mrow0 + quad * 4 + i;
    float gr = bir + bhr + acc[0][i];
    float gz = biz + bhz + acc[1][i];
    float rr = 1.f / (1.f + __expf(-gr));
    float zz = 1.f / (1.f + __expf(-gz));
    float gn = bin + rr * (acc[2][i] + bhn);
    float nn = 1.f - 2.f / (1.f + __expf(2.f * gn));
    float hold = bf2f(hoh[i]) + bf2f(hol[i]);
    float hn = (1.f - zz) * nn + zz * hold;
    size_t idx = (size_t)r * Hn + j;
    unsigned short hb = f2bf(hn);
    hhi_out[idx] = hb;
    hlo_out[idx] = f2bf(hn - bf2f(hb));
    fcv[i] = hn * fw;
  }
#pragma unroll
  for (int i = 0; i < 4; ++i) {
    fcv[i] += __shfl_xor(fcv[i], 1);
    fcv[i] += __shfl_xor(fcv[i], 2);
    fcv[i] += __shfl_xor(fcv[i], 4);
    fcv[i] += __shfl_xor(fcv[i], 8);
  }
  if (ln15 == 0) {
#pragma unroll
    for (int i = 0; i < 4; ++i)
      atomicAdd(&ddot_t[mrow0 + quad * 4 + i], fcv[i]);
  }
}

// ---------------------------------------------------------------------------
// Post: softplus -> inclusive scan over T -> normalize -> assemble output.
// ---------------------------------------------------------------------------
__global__ void post_k(const float* __restrict__ ddot,
                       const float* __restrict__ fc_b,
                       const int* __restrict__ npred, float* __restrict__ out) {
  const int b = blockIdx.x;
  const int t = threadIdx.x;  // 0..127
  __shared__ float s[Tn];
  float x = ddot[(size_t)t * Bn + b] + fc_b[0];
  float sp = (x > 20.f) ? x : log1pf(__expf(x));
  s[t] = sp;
  __syncthreads();
  for (int off = 1; off < Tn; off <<= 1) {
    float v = s[t];
    float add = (t >= off) ? s[t - off] : 0.f;
    __syncthreads();
    s[t] = v + add;
    __syncthreads();
  }
  const int n = npred[b];
  const float last = s[n - 1] + 1e-6f;
  float body = (t < n) ? (s[t] / last) : 0.f;
  float* ob = out + (size_t)b * (Tn + 2);
  ob[1 + t] = body;
  if (t == 0) { ob[0] = 0.f; ob[Tn + 1] = 0.f; }
  __syncthreads();
  if (t == 0) ob[n + 1] = 1.f;
}

// ---------------------------------------------------------------------------
extern "C" void kernel_launch(void* const* d_in, const int* in_sizes, int n_in,
                              void* d_out, int out_size, void* d_ws, size_t ws_size,
                              hipStream_t stream) {
  const float* context   = (const float*)d_in[0];
  // d_in[1] = weight_ih: unused by the reference computation
  const float* weight_hh = (const float*)d_in[2];
  const float* bias_ih   = (const float*)d_in[3];
  const float* bias_hh   = (const float*)d_in[4];
  const float* fc_w      = (const float*)d_in[5];
  const float* fc_b      = (const float*)d_in[6];
  const int*   npred     = (const int*)d_in[7];
  float* out = (float*)d_out;

  char* ws = (char*)d_ws;
  size_t o = 0;
  unsigned short* hbase = (unsigned short*)(ws + o); o += (size_t)4 * Bn * Hn * 2;
  unsigned short* wsw   = (unsigned short*)(ws + o); o += (size_t)6 * Hn * Hn * 2;
  float* ddot = (float*)(ws + o); o += (size_t)Tn * Bn * 4;
  int* flags = (int*)(ws + o); o += (size_t)RGn * 128 * 4;
  // ~8.8 MB of d_ws

  swz_w<<<dim3((2304 * (Hn / 8) + 255) / 256), dim3(256), 0, stream>>>(weight_hh, wsw);
  init_h<<<dim3((Bn * Hn + 255) / 256), dim3(256), 0, stream>>>(context, hbase, ddot, flags);

  hipFuncSetAttribute((const void*)gru_all,
                      hipFuncAttributeMaxDynamicSharedMemorySize, SMEM_BYTES);

  const unsigned short* wsw_c = wsw;
  unsigned short* hb = hbase;
  const float* bih = bias_ih;
  const float* bhh = bias_hh;
  const float* fcw = fc_w;
  float* dd = ddot;
  int* fp = flags;
  void* args[] = {(void*)&wsw_c, (void*)&hb, (void*)&bih,
                  (void*)&bhh,  (void*)&fcw, (void*)&dd, (void*)&fp};
  hipError_t ce = hipLaunchCooperativeKernel((const void*)gru_all, dim3(NBLK),
                                             dim3(NTHR), args, SMEM_BYTES, stream);
  if (ce != hipSuccess) {
    // Fallback: proven per-step dispatch path (coherence via dispatch boundary)
    hipFuncSetAttribute((const void*)gru_step,
                        hipFuncAttributeMaxDynamicSharedMemorySize, SMEM_BYTES);
    const size_t N = (size_t)Bn * Hn;
    unsigned short* HHI[2] = {hbase, hbase + 2 * N};
    unsigned short* HLO[2] = {hbase + N, hbase + 3 * N};
    int cur = 0;
    for (int t = 0; t < Tn; ++t) {
      gru_step<<<dim3(CBn, RGn), dim3(NTHR), SMEM_BYTES, stream>>>(
          wsw, HHI[cur], HLO[cur], HHI[1 - cur], HLO[1 - cur],
          bias_ih, bias_hh, fc_w, ddot + (size_t)t * Bn);
      cur ^= 1;
    }
  }

  post_k<<<dim3(Bn), dim3(Tn), 0, stream>>>(ddot, fc_b, npred, out);
}

// Round 7
// 2247.098 us; speedup vs baseline: 1.1392x; 1.1392x over previous
//
#include <hip/hip_runtime.h>
#include <stdint.h>

// Problem constants (fixed by setup_inputs)
#define Bn 256
#define Hn 768
#define Tn 128
#define KS 24      // Hn/32 ksteps
#define CBn 48     // col-blocks (j-tiles of 16 hidden units x 3 gates)
#define RGn 4      // row-groups of 64 batch rows
#define NTHR 256   // 4 waves; wave w owns m-tile w (16 rows), all gates, full K
#define NBLK 192   // CBn * RGn
#define SMEM_BYTES 147456  // W slice hi+lo in LDS (dynamic)

typedef __attribute__((ext_vector_type(8))) short short8;   // 8 bf16
typedef __attribute__((ext_vector_type(4))) float floatx4;  // mfma C/D

static __device__ __forceinline__ unsigned short f2bf(float f) {
  unsigned int x = __float_as_uint(f);
  x += 0x7fffu + ((x >> 16) & 1u);
  return (unsigned short)(x >> 16);
}
static __device__ __forceinline__ float bf2f(unsigned short u) {
  return __uint_as_float(((unsigned int)u) << 16);
}

// Device-coherent loads (r6-proven correct): agent-scope relaxed atomics read
// at the L3 coherence point where producer sc1 stores land; stale per-XCD L2
// is never consulted, so NO cache invalidate is needed anywhere.
static __device__ __forceinline__ short8 ld_coh16(const unsigned short* p) {
  union { unsigned long long u[2]; short8 v; } r;
  const unsigned long long* q = (const unsigned long long*)p;
  r.u[0] = __hip_atomic_load(q,     __ATOMIC_RELAXED, __HIP_MEMORY_SCOPE_AGENT);
  r.u[1] = __hip_atomic_load(q + 1, __ATOMIC_RELAXED, __HIP_MEMORY_SCOPE_AGENT);
  return r.v;
}
static __device__ __forceinline__ unsigned int ld_coh4(const unsigned short* p) {
  return __hip_atomic_load((const unsigned int*)p, __ATOMIC_RELAXED,
                           __HIP_MEMORY_SCOPE_AGENT);
}

// ---------------------------------------------------------------------------
// Swizzle W_hh (2304x768 fp32 row-major) into slice-contiguous B-fragment
// order, bf16 hi/lo interleaved per chunk (unchanged).
// ---------------------------------------------------------------------------
__global__ void swz_w(const float* __restrict__ W,
                      unsigned short* __restrict__ wsw) {
  int i = blockIdx.x * blockDim.x + threadIdx.x;
  if (i >= 2304 * (Hn / 8)) return;
  int n  = i / (Hn / 8);
  int k0 = (i % (Hn / 8)) * 8;
  int g = n / Hn, jj = n % Hn;
  int cb = jj >> 4, l15 = jj & 15;
  int ks = k0 >> 5, k8 = (k0 >> 3) & 3;
  int lane = l15 + 16 * k8;
  unsigned short* slice = wsw + (size_t)cb * 73728;
  size_t offh = ((size_t)((g * KS + ks) * 2 + 0)) * 512 + (size_t)lane * 8;
  size_t offl = ((size_t)((g * KS + ks) * 2 + 1)) * 512 + (size_t)lane * 8;
  const float* src = W + (size_t)n * Hn + k0;
  short8 h8, l8;
#pragma unroll
  for (int q = 0; q < 8; ++q) {
    float w = src[q];
    unsigned short hb = f2bf(w);
    h8[q] = (short)hb;
    l8[q] = (short)f2bf(w - bf2f(hb));
  }
  *(short8*)(slice + offh) = h8;
  *(short8*)(slice + offl) = l8;
}

// ---------------------------------------------------------------------------
// Init: h0 planes (bf16 hi/lo) from context; zero ddot; zero flags.
// hbase layout: [hhi0 | hlo0 | hhi1 | hlo1], each Bn*Hn elements.
// ---------------------------------------------------------------------------
__global__ void init_h(const float* __restrict__ ctx,
                       unsigned short* __restrict__ hbase,
                       float* __restrict__ ddot, int* __restrict__ flags) {
  int i = blockIdx.x * blockDim.x + threadIdx.x;
  if (i < Bn * Hn) {
    float c = ctx[i];
    unsigned short hb = f2bf(c);
    hbase[i] = hb;                            // hhi0
    hbase[Bn * Hn + i] = f2bf(c - bf2f(hb));  // hlo0
  }
  if (i < Tn * Bn) ddot[i] = 0.f;
  if (i < RGn * 128) flags[i] = 0;
}

// ---------------------------------------------------------------------------
// PERSISTENT cooperative kernel -- DATAFLOW gating, NO inter-step barrier.
//  r1-r6 lesson: every full-barrier variant costs 17.7-19.5 us/step vs a
//  ~7-8 us arithmetic floor; the lockstep barrier serializes (max over 48
//  blocks) + a chain of L3 round trips every step. So: remove the barrier
//  from the critical path entirely.
//  - RAW gating, per kstep: kstep ks of step t needs only the 32 h-cols
//    produced by blocks {2ks, 2ks+1} (flag pair >= t). One b64 atomic load
//    covers both flags; a 4-deep register ring prefetches pair ks+4 while
//    computing ks, so the check is latency-hidden and usually instant
//    (producers finished ~one full step earlier).
//  - WAR gating: before storing h_{t+1} (into buf[(t+1)&1], last read at
//    step t-1), require ALL 48 flags >= t. Checked AFTER my GEMM -- the
//    stragglers had a full step of slack; normally zero wait.
//  - flag[cb] = t+1 is stored only after vmcnt(0)-drain of the block's sc1
//    h stores + __syncthreads (r4-proven release chain). Monotone epochs;
//    induction over steps => deadlock-free. Spin guards = hang insurance.
//  - Numerics: K accumulated in ascending ks order, same epilogue =>
//    bit-identical to all previous versions.
// ---------------------------------------------------------------------------
__global__ __launch_bounds__(NTHR, 1) void gru_all(
    const unsigned short* __restrict__ wsw,
    unsigned short* hbase,
    const float* __restrict__ bias_ih, const float* __restrict__ bias_hh,
    const float* __restrict__ fc_w, float* __restrict__ ddot,
    int* flags) {
  extern __shared__ char smem[];
  unsigned short* lds_w = (unsigned short*)smem;  // 144 chunks x 1 KiB

  const int bid = blockIdx.x;              // 0..191
  const int rg = (bid & 7) >> 1;           // XCD pair -> one row-group
  const int cb = ((bid >> 3) << 1) | (bid & 1);
  const int tid = threadIdx.x;
  const int lane = tid & 63;
  const int wave = tid >> 6;
  const int ln15 = lane & 15, quad = lane >> 4;

  // ---- async W staging, ONCE ----
  const unsigned short* wsrc = wsw + (size_t)cb * 73728;
  for (int i = 0; i < 36; ++i) {
    const int c = wave * 36 + i;
    __builtin_amdgcn_global_load_lds(
        (const __attribute__((address_space(1))) unsigned int*)(wsrc + (size_t)c * 512 + lane * 8),
        (__attribute__((address_space(3))) unsigned int*)(lds_w + (size_t)c * 512),
        16, 0, 0);
  }

  // ---- per-lane constants ----
  const int j = cb * 16 + ln15;
  const float bir = bias_ih[j], biz = bias_ih[Hn + j], bin = bias_ih[2 * Hn + j];
  const float bhr = bias_hh[j], bhz = bias_hh[Hn + j], bhn = bias_hh[2 * Hn + j];
  const float fw = fc_w[j];
  const int mrow0 = rg * 64 + wave * 16;  // wave's 16 rows
  const size_t N = (size_t)Bn * Hn;
  const bool evenlane = ((ln15 & 1) == 0);
  const bool oddj = (ln15 & 1);
  int* const flagbase = flags + rg * 128;
  int* const myflag = flagbase + cb;
  const unsigned long long* const pair64 = (const unsigned long long*)flagbase;
  int* const warp_poll = flagbase + ((lane < CBn) ? lane : (CBn - 1));

  __syncthreads();  // drains vmcnt(0): W staging complete; W read-only after

  float fcv[4];

  for (int t = 0; t < Tn; ++t) {
    const unsigned short* hhi_in = hbase + (size_t)(t & 1) * (2 * N);
    const unsigned short* hlo_in = hhi_in + N;
    unsigned short* hhi_out = hbase + (size_t)((t & 1) ^ 1) * (2 * N);
    unsigned short* hlo_out = hhi_out + N;

    const unsigned short* Ah_base = hhi_in + (size_t)(mrow0 + ln15) * Hn + quad * 8;
    const unsigned short* Al_base = hlo_in + (size_t)(mrow0 + ln15) * Hn + quad * 8;

    // h_old (epilogue inputs): MY OWN columns, produced by this block last
    // step and drained before our flag -- no gating needed.
    unsigned int hd[4], ldw[4];
#pragma unroll
    for (int i = 0; i < 4; ++i) {
      size_t ridx = (size_t)(mrow0 + quad * 4 + i) * Hn + (size_t)(j & ~1);
      hd[i]  = ld_coh4(hhi_in + ridx);
      ldw[i] = ld_coh4(hlo_in + ridx);
    }

    // slow-path verifier: reload pair idx until both flags >= t (guarded)
    auto vfy = [&](unsigned long long v, int idx) {
      int a = (int)(unsigned int)(v & 0xffffffffull);
      int b = (int)(unsigned int)(v >> 32);
      if (a < t || b < t) {
        int guard = 0;
        for (;;) {
          unsigned long long w = __hip_atomic_load(
              pair64 + idx, __ATOMIC_RELAXED, __HIP_MEMORY_SCOPE_AGENT);
          a = (int)(unsigned int)(w & 0xffffffffull);
          b = (int)(unsigned int)(w >> 32);
          if (a >= t && b >= t) break;
          if (++guard > (1 << 21)) break;  // hang insurance
          __builtin_amdgcn_s_sleep(1);
        }
      }
    };

    // ---- RAW-gated A pipeline prologue: pairs 0..3 ----
    unsigned long long vf[4];
#pragma unroll
    for (int i = 0; i < 4; ++i)
      vf[i] = __hip_atomic_load(pair64 + i, __ATOMIC_RELAXED,
                                __HIP_MEMORY_SCOPE_AGENT);
    short8 Ah[4], Al[4];
#pragma unroll
    for (int p = 0; p < 4; ++p) {
      vfy(vf[p], p);
      vf[p] = __hip_atomic_load(pair64 + p + 4, __ATOMIC_RELAXED,
                                __HIP_MEMORY_SCOPE_AGENT);  // prefetch p+4
      Ah[p] = ld_coh16(Ah_base + p * 32);
      Al[p] = ld_coh16(Al_base + p * 32);
    }

    floatx4 acc[3];
#pragma unroll
    for (int g = 0; g < 3; ++g) acc[g] = (floatx4){0.f, 0.f, 0.f, 0.f};

    // ---- K-loop: compute ks (slot s), then verify+issue kstep ks+4 ----
#pragma unroll
    for (int ks = 0; ks < 24; ++ks) {
      const int s = ks & 3;
#pragma unroll
      for (int g = 0; g < 3; ++g) {
        const int cbase = ((g * KS + ks) * 2) * 512 + lane * 8;
        short8 Bh = *(const short8*)(lds_w + cbase);
        short8 Bl = *(const short8*)(lds_w + cbase + 512);
        acc[g] = __builtin_amdgcn_mfma_f32_16x16x32_bf16(Ah[s], Bh, acc[g], 0, 0, 0);
        acc[g] = __builtin_amdgcn_mfma_f32_16x16x32_bf16(Al[s], Bh, acc[g], 0, 0, 0);
        acc[g] = __builtin_amdgcn_mfma_f32_16x16x32_bf16(Ah[s], Bl, acc[g], 0, 0, 0);
      }
      if (ks + 4 < 24) {
        const int p = ks + 4;
        vfy(vf[s], p);
        if (p + 4 < 24)
          vf[s] = __hip_atomic_load(pair64 + p + 4, __ATOMIC_RELAXED,
                                    __HIP_MEMORY_SCOPE_AGENT);
        Ah[s] = ld_coh16(Ah_base + p * 32);
        Al[s] = ld_coh16(Al_base + p * 32);
      }
    }

    // ---- WAR gate: all same-rg blocks finished step t-1 (one-step slack;
    //      normally already true) ----
    {
      int guard = 0;
      for (;;) {
        int v = __hip_atomic_load(warp_poll, __ATOMIC_RELAXED,
                                  __HIP_MEMORY_SCOPE_AGENT);
        if (__all(v >= t)) break;
        if (++guard > (1 << 21)) break;  // hang insurance
        __builtin_amdgcn_s_sleep(2);
      }
    }

    // ---- epilogue: gates + h_new + fc partial (identical numerics) ----
    unsigned int ph[4], pl[4];
#pragma unroll
    for (int i = 0; i < 4; ++i) {
      float gr = bir + bhr + acc[0][i];
      float gz = biz + bhz + acc[1][i];
      float rr = 1.f / (1.f + __expf(-gr));
      float zz = 1.f / (1.f + __expf(-gz));
      float gn = bin + rr * (acc[2][i] + bhn);
      float nn = 1.f - 2.f / (1.f + __expf(2.f * gn));  // tanh
      unsigned short uh = oddj ? (unsigned short)(hd[i] >> 16)
                               : (unsigned short)(hd[i] & 0xffffu);
      unsigned short ul = oddj ? (unsigned short)(ldw[i] >> 16)
                               : (unsigned short)(ldw[i] & 0xffffu);
      float hold = bf2f(uh) + bf2f(ul);
      float hn = (1.f - zz) * nn + zz * hold;
      unsigned short hb = f2bf(hn);
      ph[i] = (unsigned int)hb;
      pl[i] = (unsigned int)f2bf(hn - bf2f(hb));
      fcv[i] = hn * fw;
    }
    // pack adjacent-j pairs (lane^1 holds j^1; same rows) -> dword sc1 stores
#pragma unroll
    for (int i = 0; i < 4; ++i) {
      unsigned int oh = (unsigned int)__shfl_xor((int)ph[i], 1);
      unsigned int ol = (unsigned int)__shfl_xor((int)pl[i], 1);
      if (evenlane) {
        size_t idx = (size_t)(mrow0 + quad * 4 + i) * Hn + j;  // j even
        __hip_atomic_store((unsigned int*)(hhi_out + idx), ph[i] | (oh << 16),
                           __ATOMIC_RELAXED, __HIP_MEMORY_SCOPE_AGENT);
        __hip_atomic_store((unsigned int*)(hlo_out + idx), pl[i] | (ol << 16),
                           __ATOMIC_RELAXED, __HIP_MEMORY_SCOPE_AGENT);
      }
    }
    // fc partial reduce in-register
#pragma unroll
    for (int i = 0; i < 4; ++i) {
      fcv[i] += __shfl_xor(fcv[i], 1);
      fcv[i] += __shfl_xor(fcv[i], 2);
      fcv[i] += __shfl_xor(fcv[i], 4);
      fcv[i] += __shfl_xor(fcv[i], 8);
    }

    // ---- release: drain h stores, then publish epoch t+1 ----
    asm volatile("s_waitcnt vmcnt(0)" ::: "memory");  // h stores acked at L3
    __syncthreads();                                  // all waves drained
    if (tid == 0)
      __hip_atomic_store(myflag, t + 1, __ATOMIC_RELAXED,
                         __HIP_MEMORY_SCOPE_AGENT);
    // ddot atomics fire-and-forget after the release (consumed by post_k;
    // drained by next step's vmcnt(0) / kernel end)
    if (ln15 == 0) {
#pragma unroll
      for (int i = 0; i < 4; ++i)
        atomicAdd(&ddot[(size_t)t * Bn + mrow0 + quad * 4 + i], fcv[i]);
    }
    // NO barrier: next step's reads are gated per-kstep on producer flags.
  }
}

// ---------------------------------------------------------------------------
// Fallback: proven one-step-per-dispatch kernel (used only if cooperative
// launch is rejected). Unchanged from the verified 1944us version.
// ---------------------------------------------------------------------------
__global__ __launch_bounds__(NTHR) void gru_step(
    const unsigned short* __restrict__ wsw,
    const unsigned short* __restrict__ hhi_in,
    const unsigned short* __restrict__ hlo_in,
    unsigned short* __restrict__ hhi_out,
    unsigned short* __restrict__ hlo_out,
    const float* __restrict__ bias_ih, const float* __restrict__ bias_hh,
    const float* __restrict__ fc_w, float* __restrict__ ddot_t) {
  extern __shared__ char smem[];
  unsigned short* lds_w = (unsigned short*)smem;

  const int cb = blockIdx.x;
  const int rg = blockIdx.y;
  const int tid = threadIdx.x;
  const int lane = tid & 63;
  const int wave = tid >> 6;
  const int ln15 = lane & 15, quad = lane >> 4;
  const int j0 = cb * 16;

  const unsigned short* wsrc = wsw + (size_t)cb * 73728;
  for (int i = 0; i < 36; ++i) {
    const int c = wave * 36 + i;
    __builtin_amdgcn_global_load_lds(
        (const __attribute__((address_space(1))) unsigned int*)(wsrc + (size_t)c * 512 + lane * 8),
        (__attribute__((address_space(3))) unsigned int*)(lds_w + (size_t)c * 512),
        16, 0, 0);
  }

  const int j = j0 + ln15;
  const float bir = bias_ih[j], biz = bias_ih[Hn + j], bin = bias_ih[2 * Hn + j];
  const float bhr = bias_hh[j], bhz = bias_hh[Hn + j], bhn = bias_hh[2 * Hn + j];
  const float fw = fc_w[j];
  const int mrow0 = rg * 64 + wave * 16;

  unsigned short hoh[4], hol[4];
#pragma unroll
  for (int i = 0; i < 4; ++i) {
    size_t idx = (size_t)(mrow0 + quad * 4 + i) * Hn + j;
    hoh[i] = hhi_in[idx];
    hol[i] = hlo_in[idx];
  }

  const unsigned short* Ah_base = hhi_in + (size_t)(mrow0 + ln15) * Hn + quad * 8;
  const unsigned short* Al_base = hlo_in + (size_t)(mrow0 + ln15) * Hn + quad * 8;

  floatx4 acc[3];
#pragma unroll
  for (int g = 0; g < 3; ++g) acc[g] = (floatx4){0.f, 0.f, 0.f, 0.f};

  short8 Abh[2][4], Abl[2][4];
#pragma unroll
  for (int q = 0; q < 4; ++q) {
    Abh[0][q] = *(const short8*)(Ah_base + q * 32);
    Abl[0][q] = *(const short8*)(Al_base + q * 32);
  }

  __syncthreads();

#pragma unroll
  for (int c = 0; c < 6; ++c) {
    const int cur = c & 1, nxt = cur ^ 1;
    if (c < 5) {
#pragma unroll
      for (int q = 0; q < 4; ++q) {
        Abh[nxt][q] = *(const short8*)(Ah_base + ((c + 1) * 4 + q) * 32);
        Abl[nxt][q] = *(const short8*)(Al_base + ((c + 1) * 4 + q) * 32);
      }
    }
#pragma unroll
    for (int kk = 0; kk < 4; ++kk) {
      const int ks = c * 4 + kk;
#pragma unroll
      for (int g = 0; g < 3; ++g) {
        const int cbase = ((g * KS + ks) * 2) * 512 + lane * 8;
        short8 Bh = *(const short8*)(lds_w + cbase);
        short8 Bl = *(const short8*)(lds_w + cbase + 512);
        acc[g] = __builtin_amdgcn_mfma_f32_16x16x32_bf16(Abh[cur][kk], Bh, acc[g], 0, 0, 0);
        acc[g] = __builtin_amdgcn_mfma_f32_16x16x32_bf16(Abl[cur][kk], Bh, acc[g], 0, 0, 0);
        acc[g] = __builtin_amdgcn_mfma_f32_16x16x32_bf16(Abh[cur][kk], Bl, acc[g], 0, 0, 0);
      }
    }
  }

  float fcv[4];
#pragma unroll
  for (int i = 0; i < 4; ++i) {
    const int r = mrow0 + quad * 4 + i;
    float gr = bir + bhr + acc[0][i];
    float gz = biz + bhz + acc[1][i];
    float rr = 1.f / (1.f + __expf(-gr));
    float zz = 1.f / (1.f + __expf(-gz));
    float gn = bin + rr * (acc[2][i] + bhn);
    float nn = 1.f - 2.f / (1.f + __expf(2.f * gn));
    float hold = bf2f(hoh[i]) + bf2f(hol[i]);
    float hn = (1.f - zz) * nn + zz * hold;
    size_t idx = (size_t)r * Hn + j;
    unsigned short hb = f2bf(hn);
    hhi_out[idx] = hb;
    hlo_out[idx] = f2bf(hn - bf2f(hb));
    fcv[i] = hn * fw;
  }
#pragma unroll
  for (int i = 0; i < 4; ++i) {
    fcv[i] += __shfl_xor(fcv[i], 1);
    fcv[i] += __shfl_xor(fcv[i], 2);
    fcv[i] += __shfl_xor(fcv[i], 4);
    fcv[i] += __shfl_xor(fcv[i], 8);
  }
  if (ln15 == 0) {
#pragma unroll
    for (int i = 0; i < 4; ++i)
      atomicAdd(&ddot_t[mrow0 + quad * 4 + i], fcv[i]);
  }
}

// ---------------------------------------------------------------------------
// Post: softplus -> inclusive scan over T -> normalize -> assemble output.
// ---------------------------------------------------------------------------
__global__ void post_k(const float* __restrict__ ddot,
                       const float* __restrict__ fc_b,
                       const int* __restrict__ npred, float* __restrict__ out) {
  const int b = blockIdx.x;
  const int t = threadIdx.x;  // 0..127
  __shared__ float s[Tn];
  float x = ddot[(size_t)t * Bn + b] + fc_b[0];
  float sp = (x > 20.f) ? x : log1pf(__expf(x));
  s[t] = sp;
  __syncthreads();
  for (int off = 1; off < Tn; off <<= 1) {
    float v = s[t];
    float add = (t >= off) ? s[t - off] : 0.f;
    __syncthreads();
    s[t] = v + add;
    __syncthreads();
  }
  const int n = npred[b];
  const float last = s[n - 1] + 1e-6f;
  float body = (t < n) ? (s[t] / last) : 0.f;
  float* ob = out + (size_t)b * (Tn + 2);
  ob[1 + t] = body;
  if (t == 0) { ob[0] = 0.f; ob[Tn + 1] = 0.f; }
  __syncthreads();
  if (t == 0) ob[n + 1] = 1.f;
}

// ---------------------------------------------------------------------------
extern "C" void kernel_launch(void* const* d_in, const int* in_sizes, int n_in,
                              void* d_out, int out_size, void* d_ws, size_t ws_size,
                              hipStream_t stream) {
  const float* context   = (const float*)d_in[0];
  // d_in[1] = weight_ih: unused by the reference computation
  const float* weight_hh = (const float*)d_in[2];
  const float* bias_ih   = (const float*)d_in[3];
  const float* bias_hh   = (const float*)d_in[4];
  const float* fc_w      = (const float*)d_in[5];
  const float* fc_b      = (const float*)d_in[6];
  const int*   npred     = (const int*)d_in[7];
  float* out = (float*)d_out;

  char* ws = (char*)d_ws;
  size_t o = 0;
  unsigned short* hbase = (unsigned short*)(ws + o); o += (size_t)4 * Bn * Hn * 2;
  unsigned short* wsw   = (unsigned short*)(ws + o); o += (size_t)6 * Hn * Hn * 2;
  float* ddot = (float*)(ws + o); o += (size_t)Tn * Bn * 4;
  int* flags = (int*)(ws + o); o += (size_t)RGn * 128 * 4;
  // ~8.8 MB of d_ws

  swz_w<<<dim3((2304 * (Hn / 8) + 255) / 256), dim3(256), 0, stream>>>(weight_hh, wsw);
  init_h<<<dim3((Bn * Hn + 255) / 256), dim3(256), 0, stream>>>(context, hbase, ddot, flags);

  hipFuncSetAttribute((const void*)gru_all,
                      hipFuncAttributeMaxDynamicSharedMemorySize, SMEM_BYTES);

  const unsigned short* wsw_c = wsw;
  unsigned short* hb = hbase;
  const float* bih = bias_ih;
  const float* bhh = bias_hh;
  const float* fcw = fc_w;
  float* dd = ddot;
  int* fp = flags;
  void* args[] = {(void*)&wsw_c, (void*)&hb, (void*)&bih,
                  (void*)&bhh,  (void*)&fcw, (void*)&dd, (void*)&fp};
  hipError_t ce = hipLaunchCooperativeKernel((const void*)gru_all, dim3(NBLK),
                                             dim3(NTHR), args, SMEM_BYTES, stream);
  if (ce != hipSuccess) {
    // Fallback: proven per-step dispatch path (coherence via dispatch boundary)
    hipFuncSetAttribute((const void*)gru_step,
                        hipFuncAttributeMaxDynamicSharedMemorySize, SMEM_BYTES);
    const size_t N = (size_t)Bn * Hn;
    unsigned short* HHI[2] = {hbase, hbase + 2 * N};
    unsigned short* HLO[2] = {hbase + N, hbase + 3 * N};
    int cur = 0;
    for (int t = 0; t < Tn; ++t) {
      gru_step<<<dim3(CBn, RGn), dim3(NTHR), SMEM_BYTES, stream>>>(
          wsw, HHI[cur], HLO[cur], HHI[1 - cur], HLO[1 - cur],
          bias_ih, bias_hh, fc_w, ddot + (size_t)t * Bn);
      cur ^= 1;
    }
  }

  post_k<<<dim3(Bn), dim3(Tn), 0, stream>>>(ddot, fc_b, npred, out);
}

// Round 8
// 1990.202 us; speedup vs baseline: 1.2862x; 1.1291x over previous
//
#include <hip/hip_runtime.h>
#include <stdint.h>

// Problem constants (fixed by setup_inputs)
#define Bn 256
#define Hn 768
#define Tn 128
#define KS 24      // Hn/32 ksteps
#define CBn 48     // col-blocks (j-tiles of 16 hidden units x 3 gates)
#define RGn 4      // row-groups of 64 batch rows
#define NTHR 256   // 4 waves
#define NBLK 192   // CBn * RGn
#define SMEM_BYTES 147456  // W slice hi+lo in LDS (dynamic)

typedef __attribute__((ext_vector_type(8))) short short8;   // 8 bf16
typedef __attribute__((ext_vector_type(4))) float floatx4;  // mfma C/D

static __device__ __forceinline__ unsigned short f2bf(float f) {
  unsigned int x = __float_as_uint(f);
  x += 0x7fffu + ((x >> 16) & 1u);
  return (unsigned short)(x >> 16);
}
static __device__ __forceinline__ float bf2f(unsigned short u) {
  return __uint_as_float(((unsigned int)u) << 16);
}

// ---------------------------------------------------------------------------
// Swizzle W_hh (2304x768 fp32 row-major) into slice-contiguous B-fragment
// order, bf16 hi/lo interleaved per chunk (unchanged, verified r0-r7).
// Slice cb: chunk c = (g*24+ks)*2 + plane, 1 KiB each; within a chunk lane L
// holds W[g*768 + cb*16 + (L&15)][ks*32 + (L>>4)*8 .. +8].
// ---------------------------------------------------------------------------
__global__ void swz_w(const float* __restrict__ W,
                      unsigned short* __restrict__ wsw) {
  int i = blockIdx.x * blockDim.x + threadIdx.x;
  if (i >= 2304 * (Hn / 8)) return;
  int n  = i / (Hn / 8);
  int k0 = (i % (Hn / 8)) * 8;
  int g = n / Hn, jj = n % Hn;
  int cb = jj >> 4, l15 = jj & 15;
  int ks = k0 >> 5, k8 = (k0 >> 3) & 3;
  int lane = l15 + 16 * k8;
  unsigned short* slice = wsw + (size_t)cb * 73728;
  size_t offh = ((size_t)((g * KS + ks) * 2 + 0)) * 512 + (size_t)lane * 8;
  size_t offl = ((size_t)((g * KS + ks) * 2 + 1)) * 512 + (size_t)lane * 8;
  const float* src = W + (size_t)n * Hn + k0;
  short8 h8, l8;
#pragma unroll
  for (int q = 0; q < 8; ++q) {
    float w = src[q];
    unsigned short hb = f2bf(w);
    h8[q] = (short)hb;
    l8[q] = (short)f2bf(w - bf2f(hb));
  }
  *(short8*)(slice + offh) = h8;
  *(short8*)(slice + offl) = l8;
}

// ---------------------------------------------------------------------------
// Init: h0 planes (bf16 hi/lo) from context; zero ddot.
// hbase layout: [hhi0 | hlo0 | hhi1 | hlo1], each Bn*Hn elements.
// ---------------------------------------------------------------------------
__global__ void init_h(const float* __restrict__ ctx,
                       unsigned short* __restrict__ hbase,
                       float* __restrict__ ddot) {
  int i = blockIdx.x * blockDim.x + threadIdx.x;
  if (i < Bn * Hn) {
    float c = ctx[i];
    unsigned short hb = f2bf(c);
    hbase[i] = hb;                            // hhi0
    hbase[Bn * Hn + i] = f2bf(c - bf2f(hb));  // hlo0
  }
  if (i < Tn * Bn) ddot[i] = 0.f;
}

// ---------------------------------------------------------------------------
// ONE GRU step per dispatch (r0-verified coherence model: normal stores ->
// dispatch boundary -> next-dispatch normal loads). r1-r7 showed every
// software sync costs MORE than the dispatch boundary, so we optimize the
// step kernel instead:
//  * K-SPLIT ACROSS WAVES: wave w owns ksteps [6w,6w+6) for ALL 4 m-tiles
//    (was: m-tile w, full K). Each wave reads only ITS 36 KiB W quarter ->
//    LDS reads drop 4x (576 -> 144+48 b128/CU/step). Partials are reduced
//    through the W LDS area, which is dead after the GEMM barrier.
//  * NO pre-GEMM __syncthreads: a wave consumes only chunks IT staged, so
//    its own s_waitcnt vmcnt(0) suffices (global_load_lds completion);
//    waves enter the K-loop independently (removes the all-wave stage
//    drain serialization).
//  * XCD-grouped remap: rg = (bid&7)>>1 pins each rg's 48 blocks to an
//    XCD pair -> the shared 192 KiB A-tile fills 2 L2s, not 8.
// Numerics: same products; K-sum associativity is (q0+q1+q2+q3) instead of
// sequential -- ~2^-20 relative perturbation vs the 2^-9 bf16-split error.
// ---------------------------------------------------------------------------
__global__ __launch_bounds__(NTHR) void gru_step(
    const unsigned short* __restrict__ wsw,
    const unsigned short* __restrict__ hhi_in,
    const unsigned short* __restrict__ hlo_in,
    unsigned short* __restrict__ hhi_out,
    unsigned short* __restrict__ hlo_out,
    const float* __restrict__ bias_ih, const float* __restrict__ bias_hh,
    const float* __restrict__ fc_w, float* __restrict__ ddot_t) {
  extern __shared__ char smem[];
  unsigned short* lds_w = (unsigned short*)smem;  // 144 chunks x 1 KiB
  float* lds_red = (float*)smem;                  // reduce area (aliases W)

  const int bid = blockIdx.x;              // 0..191
  const int rg = (bid & 7) >> 1;           // XCD pair -> one row-group
  const int cb = ((bid >> 3) << 1) | (bid & 1);
  const int tid = threadIdx.x;
  const int lane = tid & 63;
  const int wave = tid >> 6;               // = K-quarter owner
  const int ln15 = lane & 15, quad = lane >> 4;
  const int ksl = wave * 6;                // this wave's first kstep

  // ---- stage ONLY this wave's W quarter (36 chunks, async 16B) ----
  const unsigned short* wsrc = wsw + (size_t)cb * 73728;
#pragma unroll
  for (int g = 0; g < 3; ++g)
#pragma unroll
    for (int kk = 0; kk < 6; ++kk)
#pragma unroll
      for (int pl = 0; pl < 2; ++pl) {
        const int c = (g * KS + ksl + kk) * 2 + pl;
        __builtin_amdgcn_global_load_lds(
            (const __attribute__((address_space(1))) unsigned int*)(wsrc + (size_t)c * 512 + lane * 8),
            (__attribute__((address_space(3))) unsigned int*)(lds_w + (size_t)c * 512),
            16, 0, 0);
      }

  // ---- per-lane constants ----
  const int j = cb * 16 + ln15;
  const float bir = bias_ih[j], biz = bias_ih[Hn + j], bin = bias_ih[2 * Hn + j];
  const float bhr = bias_hh[j], bhz = bias_hh[Hn + j], bhn = bias_hh[2 * Hn + j];
  const float fw = fc_w[j];
  const int mrow0 = rg * 64 + wave * 16;   // epilogue rows (m-tile = wave)

  // h_old loads (epilogue inputs) issued early; latency hidden by GEMM
  unsigned short hoh[4], hol[4];
#pragma unroll
  for (int i = 0; i < 4; ++i) {
    size_t idx = (size_t)(mrow0 + quad * 4 + i) * Hn + j;
    hoh[i] = hhi_in[idx];
    hol[i] = hlo_in[idx];
  }

  // A bases for all 4 m-tiles (this wave reads k-slices of every m-tile)
  const unsigned short* AhB[4];
  const unsigned short* AlB[4];
#pragma unroll
  for (int m = 0; m < 4; ++m) {
    AhB[m] = hhi_in + (size_t)(rg * 64 + m * 16 + ln15) * Hn + quad * 8;
    AlB[m] = hlo_in + (size_t)(rg * 64 + m * 16 + ln15) * Hn + quad * 8;
  }

  // A prologue: slot 0 = kstep ksl (4 m-tiles x hi/lo)
  short8 Ah[2][4], Al[2][4];
#pragma unroll
  for (int m = 0; m < 4; ++m) {
    Ah[0][m] = *(const short8*)(AhB[m] + ksl * 32);
    Al[0][m] = *(const short8*)(AlB[m] + ksl * 32);
  }

  // Drain: own W stages (and the loads above) complete; no block barrier.
  asm volatile("s_waitcnt vmcnt(0)" ::: "memory");
  __builtin_amdgcn_sched_barrier(0);  // rule #18: nothing hoists above

  floatx4 acc[4][3];
#pragma unroll
  for (int m = 0; m < 4; ++m)
#pragma unroll
    for (int g = 0; g < 3; ++g) acc[m][g] = (floatx4){0.f, 0.f, 0.f, 0.f};

  // ---- K-quarter loop: 6 ksteps, each B-read feeds 4 m-tiles (4x reuse) ----
#pragma unroll
  for (int kk = 0; kk < 6; ++kk) {
    const int cur = kk & 1, nxt = cur ^ 1;
    if (kk < 5) {
      const int ksn = ksl + kk + 1;
#pragma unroll
      for (int m = 0; m < 4; ++m) {
        Ah[nxt][m] = *(const short8*)(AhB[m] + ksn * 32);
        Al[nxt][m] = *(const short8*)(AlB[m] + ksn * 32);
      }
    }
    const int ks = ksl + kk;
#pragma unroll
    for (int g = 0; g < 3; ++g) {
      const int cbase = ((g * KS + ks) * 2) * 512 + lane * 8;
      short8 Bh = *(const short8*)(lds_w + cbase);
      short8 Bl = *(const short8*)(lds_w + cbase + 512);
#pragma unroll
      for (int m = 0; m < 4; ++m) {
        acc[m][g] = __builtin_amdgcn_mfma_f32_16x16x32_bf16(Ah[cur][m], Bh, acc[m][g], 0, 0, 0);
        acc[m][g] = __builtin_amdgcn_mfma_f32_16x16x32_bf16(Al[cur][m], Bh, acc[m][g], 0, 0, 0);
        acc[m][g] = __builtin_amdgcn_mfma_f32_16x16x32_bf16(Ah[cur][m], Bl, acc[m][g], 0, 0, 0);
      }
    }
  }

  // ---- cross-wave K-reduction through the (now dead) W LDS area ----
  // layout: off(v,m,g) = ((v*4+m)*3+g)*1024B + lane*16B   (48 KiB total)
  __syncthreads();  // all waves done READING W -> safe to overwrite
#pragma unroll
  for (int m = 0; m < 4; ++m)
#pragma unroll
    for (int g = 0; g < 3; ++g)
      *(floatx4*)((char*)lds_red + (size_t)(((wave * 4 + m) * 3 + g)) * 1024 + lane * 16) = acc[m][g];
  __syncthreads();

  floatx4 facc[3];
#pragma unroll
  for (int g = 0; g < 3; ++g) {
    floatx4 s = (floatx4){0.f, 0.f, 0.f, 0.f};
#pragma unroll
    for (int v = 0; v < 4; ++v)
      s += *(const floatx4*)((char*)lds_red + (size_t)(((v * 4 + wave) * 3 + g)) * 1024 + lane * 16);
    facc[g] = s;
  }

  // ---- epilogue: gates + h_new + fc partial (formulas unchanged) ----
  float fcv[4];
#pragma unroll
  for (int i = 0; i < 4; ++i) {
    const int r = mrow0 + quad * 4 + i;  // C/D layout: row = quad*4 + i
    float gr = bir + bhr + facc[0][i];
    float gz = biz + bhz + facc[1][i];
    float rr = 1.f / (1.f + __expf(-gr));
    float zz = 1.f / (1.f + __expf(-gz));
    float gn = bin + rr * (facc[2][i] + bhn);
    float nn = 1.f - 2.f / (1.f + __expf(2.f * gn));  // tanh
    float hold = bf2f(hoh[i]) + bf2f(hol[i]);
    float hn = (1.f - zz) * nn + zz * hold;
    size_t idx = (size_t)r * Hn + j;
    unsigned short hb = f2bf(hn);
    hhi_out[idx] = hb;                  // normal stores; CP flushes at boundary
    hlo_out[idx] = f2bf(hn - bf2f(hb));
    fcv[i] = hn * fw;
  }
#pragma unroll
  for (int i = 0; i < 4; ++i) {
    fcv[i] += __shfl_xor(fcv[i], 1);
    fcv[i] += __shfl_xor(fcv[i], 2);
    fcv[i] += __shfl_xor(fcv[i], 4);
    fcv[i] += __shfl_xor(fcv[i], 8);
  }
  if (ln15 == 0) {
#pragma unroll
    for (int i = 0; i < 4; ++i)
      atomicAdd(&ddot_t[mrow0 + quad * 4 + i], fcv[i]);
  }
}

// ---------------------------------------------------------------------------
// Post: softplus -> inclusive scan over T -> normalize -> assemble output.
// ---------------------------------------------------------------------------
__global__ void post_k(const float* __restrict__ ddot,
                       const float* __restrict__ fc_b,
                       const int* __restrict__ npred, float* __restrict__ out) {
  const int b = blockIdx.x;
  const int t = threadIdx.x;  // 0..127
  __shared__ float s[Tn];
  float x = ddot[(size_t)t * Bn + b] + fc_b[0];
  float sp = (x > 20.f) ? x : log1pf(__expf(x));
  s[t] = sp;
  __syncthreads();
  for (int off = 1; off < Tn; off <<= 1) {
    float v = s[t];
    float add = (t >= off) ? s[t - off] : 0.f;
    __syncthreads();
    s[t] = v + add;
    __syncthreads();
  }
  const int n = npred[b];
  const float last = s[n - 1] + 1e-6f;
  float body = (t < n) ? (s[t] / last) : 0.f;
  float* ob = out + (size_t)b * (Tn + 2);
  ob[1 + t] = body;
  if (t == 0) { ob[0] = 0.f; ob[Tn + 1] = 0.f; }
  __syncthreads();
  if (t == 0) ob[n + 1] = 1.f;
}

// ---------------------------------------------------------------------------
extern "C" void kernel_launch(void* const* d_in, const int* in_sizes, int n_in,
                              void* d_out, int out_size, void* d_ws, size_t ws_size,
                              hipStream_t stream) {
  const float* context   = (const float*)d_in[0];
  // d_in[1] = weight_ih: unused by the reference computation
  const float* weight_hh = (const float*)d_in[2];
  const float* bias_ih   = (const float*)d_in[3];
  const float* bias_hh   = (const float*)d_in[4];
  const float* fc_w      = (const float*)d_in[5];
  const float* fc_b      = (const float*)d_in[6];
  const int*   npred     = (const int*)d_in[7];
  float* out = (float*)d_out;

  char* ws = (char*)d_ws;
  size_t o = 0;
  unsigned short* hbase = (unsigned short*)(ws + o); o += (size_t)4 * Bn * Hn * 2;
  unsigned short* wsw   = (unsigned short*)(ws + o); o += (size_t)6 * Hn * Hn * 2;
  float* ddot = (float*)(ws + o); o += (size_t)Tn * Bn * 4;
  // ~8.8 MB of d_ws

  const size_t N = (size_t)Bn * Hn;
  unsigned short* HHI[2] = {hbase, hbase + 2 * N};
  unsigned short* HLO[2] = {hbase + N, hbase + 3 * N};

  swz_w<<<dim3((2304 * (Hn / 8) + 255) / 256), dim3(256), 0, stream>>>(weight_hh, wsw);
  init_h<<<dim3((Bn * Hn + 255) / 256), dim3(256), 0, stream>>>(context, hbase, ddot);

  hipFuncSetAttribute((const void*)gru_step,
                      hipFuncAttributeMaxDynamicSharedMemorySize, SMEM_BYTES);

  int cur = 0;
  for (int t = 0; t < Tn; ++t) {
    gru_step<<<dim3(NBLK), dim3(NTHR), SMEM_BYTES, stream>>>(
        wsw, HHI[cur], HLO[cur], HHI[1 - cur], HLO[1 - cur],
        bias_ih, bias_hh, fc_w, ddot + (size_t)t * Bn);
    cur ^= 1;
  }

  post_k<<<dim3(Bn), dim3(Tn), 0, stream>>>(ddot, fc_b, npred, out);
}

// Round 9
// 1937.400 us; speedup vs baseline: 1.3213x; 1.0273x over previous
//
#include <hip/hip_runtime.h>
#include <stdint.h>

// Problem constants (fixed by setup_inputs)
#define Bn 256
#define Hn 768
#define Tn 128
#define KS 24      // Hn/32 ksteps
#define CBn 48     // col-blocks (j-tiles of 16 hidden units x 3 gates)
#define RGn 4      // row-groups of 64 batch rows
#define NTHR 256   // 4 waves; wave w owns m-tile w (16 rows), all gates, full K
#define SMEM_BYTES 147456  // W slice hi+lo in LDS (dynamic)

typedef __attribute__((ext_vector_type(8))) short short8;   // 8 bf16
typedef __attribute__((ext_vector_type(4))) float floatx4;  // mfma C/D

static __device__ __forceinline__ unsigned short f2bf(float f) {
  unsigned int x = __float_as_uint(f);
  x += 0x7fffu + ((x >> 16) & 1u);
  return (unsigned short)(x >> 16);
}
static __device__ __forceinline__ float bf2f(unsigned short u) {
  return __uint_as_float(((unsigned int)u) << 16);
}

// ---------------------------------------------------------------------------
// Swizzle W_hh (2304x768 fp32 row-major) into slice-contiguous B-fragment
// order, bf16 hi/lo interleaved per chunk. Slice cb (147456 B): chunk
// c = (g*24+ks)*2 + plane, 1 KiB each; within a chunk lane L holds
// W[g*768 + cb*16 + (L&15)][ks*32 + (L>>4)*8 .. +8].
// Slice-contiguous => per-step LDS staging is a linear async copy.
// ---------------------------------------------------------------------------
__global__ void swz_w(const float* __restrict__ W,
                      unsigned short* __restrict__ wsw) {
  int i = blockIdx.x * blockDim.x + threadIdx.x;
  if (i >= 2304 * (Hn / 8)) return;
  int n  = i / (Hn / 8);
  int k0 = (i % (Hn / 8)) * 8;
  int g = n / Hn, jj = n % Hn;
  int cb = jj >> 4, l15 = jj & 15;
  int ks = k0 >> 5, k8 = (k0 >> 3) & 3;
  int lane = l15 + 16 * k8;
  unsigned short* slice = wsw + (size_t)cb * 73728;
  size_t offh = ((size_t)((g * KS + ks) * 2 + 0)) * 512 + (size_t)lane * 8;
  size_t offl = ((size_t)((g * KS + ks) * 2 + 1)) * 512 + (size_t)lane * 8;
  const float* src = W + (size_t)n * Hn + k0;
  short8 h8, l8;
#pragma unroll
  for (int q = 0; q < 8; ++q) {
    float w = src[q];
    unsigned short hb = f2bf(w);
    h8[q] = (short)hb;
    l8[q] = (short)f2bf(w - bf2f(hb));
  }
  *(short8*)(slice + offh) = h8;
  *(short8*)(slice + offl) = l8;
}

// ---------------------------------------------------------------------------
// Init: h0 planes (bf16 hi/lo) from context; zero ddot.
// hbase layout: [hhi0 | hlo0 | hhi1 | hlo1], each Bn*Hn elements.
// ---------------------------------------------------------------------------
__global__ void init_h(const float* __restrict__ ctx,
                       unsigned short* __restrict__ hbase,
                       float* __restrict__ ddot) {
  int i = blockIdx.x * blockDim.x + threadIdx.x;
  if (i < Bn * Hn) {
    float c = ctx[i];
    unsigned short hb = f2bf(c);
    hbase[i] = hb;                            // hhi0
    hbase[Bn * Hn + i] = f2bf(c - bf2f(hb));  // hlo0
  }
  if (i < Tn * Bn) ddot[i] = 0.f;
}

// ---------------------------------------------------------------------------
// ONE GRU step per dispatch — coherence via the dispatch boundary (proven
// R1: normal stores -> next-dispatch normal loads, incl. ping-pong reuse).
// Block (cb, rg): stages W slice cb into LDS via async global_load_lds
// (width 16, 36 chunks/wave, drained by the s_waitcnt vmcnt(0) that
// __syncthreads emits), then the R7 K-loop: wave w owns m-tile w (16 rows),
// all 3 gates, full K, split-bf16 (3 MFMAs/product). No fences, no flags.
//
// Session r1-r8 verdict: every software sync (grid.sync, atomic counter,
// flag arrays, two-level, fenceless L3-direct, dataflow gating) costs
// 17.3-29.6 us/step vs this kernel's 15.2, and in-kernel micro-opts
// (K-split 4x LDS-read cut, no-barrier stage, XCD remap) are neutral --
// the per-step cost is the producer->consumer turnaround itself. This
// configuration is the measured floor.
// ---------------------------------------------------------------------------
__global__ __launch_bounds__(NTHR) void gru_step(
    const unsigned short* __restrict__ wsw,
    const unsigned short* __restrict__ hhi_in,
    const unsigned short* __restrict__ hlo_in,
    unsigned short* __restrict__ hhi_out,
    unsigned short* __restrict__ hlo_out,
    const float* __restrict__ bias_ih, const float* __restrict__ bias_hh,
    const float* __restrict__ fc_w, float* __restrict__ ddot_t) {
  extern __shared__ char smem[];
  unsigned short* lds_w = (unsigned short*)smem;  // 144 chunks x 1 KiB

  const int cb = blockIdx.x;      // 0..47
  const int rg = blockIdx.y;      // 0..3
  const int tid = threadIdx.x;
  const int lane = tid & 63;
  const int wave = tid >> 6;
  const int ln15 = lane & 15, quad = lane >> 4;
  const int j0 = cb * 16;

  // ---- async W staging: wave w stages chunks [36w, 36w+36) ----
  const unsigned short* wsrc = wsw + (size_t)cb * 73728;
  for (int i = 0; i < 36; ++i) {
    const int c = wave * 36 + i;
    __builtin_amdgcn_global_load_lds(
        (const __attribute__((address_space(1))) unsigned int*)(wsrc + (size_t)c * 512 + lane * 8),
        (__attribute__((address_space(3))) unsigned int*)(lds_w + (size_t)c * 512),
        16, 0, 0);
  }

  // ---- per-lane constants ----
  const int j = j0 + ln15;
  const float bir = bias_ih[j], biz = bias_ih[Hn + j], bin = bias_ih[2 * Hn + j];
  const float bhr = bias_hh[j], bhz = bias_hh[Hn + j], bhn = bias_hh[2 * Hn + j];
  const float fw = fc_w[j];
  const int mrow0 = rg * 64 + wave * 16;  // wave's 16 rows

  // h_old loads (epilogue inputs) issued early; latency hidden by GEMM
  unsigned short hoh[4], hol[4];
#pragma unroll
  for (int i = 0; i < 4; ++i) {
    size_t idx = (size_t)(mrow0 + quad * 4 + i) * Hn + j;
    hoh[i] = hhi_in[idx];
    hol[i] = hlo_in[idx];
  }

  const unsigned short* Ah_base = hhi_in + (size_t)(mrow0 + ln15) * Hn + quad * 8;
  const unsigned short* Al_base = hlo_in + (size_t)(mrow0 + ln15) * Hn + quad * 8;

  floatx4 acc[3];
#pragma unroll
  for (int g = 0; g < 3; ++g) acc[g] = (floatx4){0.f, 0.f, 0.f, 0.f};

  // first A chunk prefetch (before the barrier: more latency overlap)
  short8 Abh[2][4], Abl[2][4];
#pragma unroll
  for (int q = 0; q < 4; ++q) {
    Abh[0][q] = *(const short8*)(Ah_base + q * 32);
    Abl[0][q] = *(const short8*)(Al_base + q * 32);
  }

  __syncthreads();  // drains vmcnt(0): W staging + A chunk 0 complete

#pragma unroll
  for (int c = 0; c < 6; ++c) {
    const int cur = c & 1, nxt = cur ^ 1;
    if (c < 5) {
#pragma unroll
      for (int q = 0; q < 4; ++q) {
        Abh[nxt][q] = *(const short8*)(Ah_base + ((c + 1) * 4 + q) * 32);
        Abl[nxt][q] = *(const short8*)(Al_base + ((c + 1) * 4 + q) * 32);
      }
    }
#pragma unroll
    for (int kk = 0; kk < 4; ++kk) {
      const int ks = c * 4 + kk;
#pragma unroll
      for (int g = 0; g < 3; ++g) {
        const int cbase = ((g * KS + ks) * 2) * 512 + lane * 8;
        short8 Bh = *(const short8*)(lds_w + cbase);
        short8 Bl = *(const short8*)(lds_w + cbase + 512);
        acc[g] = __builtin_amdgcn_mfma_f32_16x16x32_bf16(Abh[cur][kk], Bh, acc[g], 0, 0, 0);
        acc[g] = __builtin_amdgcn_mfma_f32_16x16x32_bf16(Abl[cur][kk], Bh, acc[g], 0, 0, 0);
        acc[g] = __builtin_amdgcn_mfma_f32_16x16x32_bf16(Abh[cur][kk], Bl, acc[g], 0, 0, 0);
      }
    }
  }

  // ---- epilogue: gates + h_new + fc partial ----
  float fcv[4];
#pragma unroll
  for (int i = 0; i < 4; ++i) {
    const int r = mrow0 + quad * 4 + i;  // C/D layout: row = quad*4 + i
    float gr = bir + bhr + acc[0][i];
    float gz = biz + bhz + acc[1][i];
    float rr = 1.f / (1.f + __expf(-gr));
    float zz = 1.f / (1.f + __expf(-gz));
    float gn = bin + rr * (acc[2][i] + bhn);
    float nn = 1.f - 2.f / (1.f + __expf(2.f * gn));  // tanh
    float hold = bf2f(hoh[i]) + bf2f(hol[i]);
    float hn = (1.f - zz) * nn + zz * hold;
    size_t idx = (size_t)r * Hn + j;
    unsigned short hb = f2bf(hn);
    hhi_out[idx] = hb;                  // normal stores; CP flushes at boundary
    hlo_out[idx] = f2bf(hn - bf2f(hb));
    fcv[i] = hn * fw;
  }
#pragma unroll
  for (int i = 0; i < 4; ++i) {
    fcv[i] += __shfl_xor(fcv[i], 1);
    fcv[i] += __shfl_xor(fcv[i], 2);
    fcv[i] += __shfl_xor(fcv[i], 4);
    fcv[i] += __shfl_xor(fcv[i], 8);
  }
  if (ln15 == 0) {
#pragma unroll
    for (int i = 0; i < 4; ++i)
      atomicAdd(&ddot_t[mrow0 + quad * 4 + i], fcv[i]);
  }
}

// ---------------------------------------------------------------------------
// Post: softplus -> inclusive scan over T -> normalize -> assemble output.
// ---------------------------------------------------------------------------
__global__ void post_k(const float* __restrict__ ddot,
                       const float* __restrict__ fc_b,
                       const int* __restrict__ npred, float* __restrict__ out) {
  const int b = blockIdx.x;
  const int t = threadIdx.x;  // 0..127
  __shared__ float s[Tn];
  float x = ddot[(size_t)t * Bn + b] + fc_b[0];
  float sp = (x > 20.f) ? x : log1pf(__expf(x));
  s[t] = sp;
  __syncthreads();
  for (int off = 1; off < Tn; off <<= 1) {
    float v = s[t];
    float add = (t >= off) ? s[t - off] : 0.f;
    __syncthreads();
    s[t] = v + add;
    __syncthreads();
  }
  const int n = npred[b];
  const float last = s[n - 1] + 1e-6f;
  float body = (t < n) ? (s[t] / last) : 0.f;
  float* ob = out + (size_t)b * (Tn + 2);
  ob[1 + t] = body;
  if (t == 0) { ob[0] = 0.f; ob[Tn + 1] = 0.f; }
  __syncthreads();
  if (t == 0) ob[n + 1] = 1.f;
}

// ---------------------------------------------------------------------------
extern "C" void kernel_launch(void* const* d_in, const int* in_sizes, int n_in,
                              void* d_out, int out_size, void* d_ws, size_t ws_size,
                              hipStream_t stream) {
  const float* context   = (const float*)d_in[0];
  // d_in[1] = weight_ih: unused by the reference computation
  const float* weight_hh = (const float*)d_in[2];
  const float* bias_ih   = (const float*)d_in[3];
  const float* bias_hh   = (const float*)d_in[4];
  const float* fc_w      = (const float*)d_in[5];
  const float* fc_b      = (const float*)d_in[6];
  const int*   npred     = (const int*)d_in[7];
  float* out = (float*)d_out;

  char* ws = (char*)d_ws;
  size_t o = 0;
  unsigned short* hbase = (unsigned short*)(ws + o); o += (size_t)4 * Bn * Hn * 2;
  unsigned short* wsw   = (unsigned short*)(ws + o); o += (size_t)6 * Hn * Hn * 2;
  float* ddot = (float*)(ws + o); o += (size_t)Tn * Bn * 4;
  // ~8.8 MB of d_ws

  const size_t N = (size_t)Bn * Hn;
  unsigned short* HHI[2] = {hbase, hbase + 2 * N};
  unsigned short* HLO[2] = {hbase + N, hbase + 3 * N};

  swz_w<<<dim3((2304 * (Hn / 8) + 255) / 256), dim3(256), 0, stream>>>(weight_hh, wsw);
  init_h<<<dim3((Bn * Hn + 255) / 256), dim3(256), 0, stream>>>(context, hbase, ddot);

  hipFuncSetAttribute((const void*)gru_step,
                      hipFuncAttributeMaxDynamicSharedMemorySize, SMEM_BYTES);

  int cur = 0;
  for (int t = 0; t < Tn; ++t) {
    gru_step<<<dim3(CBn, RGn), dim3(NTHR), SMEM_BYTES, stream>>>(
        wsw, HHI[cur], HLO[cur], HHI[1 - cur], HLO[1 - cur],
        bias_ih, bias_hh, fc_w, ddot + (size_t)t * Bn);
    cur ^= 1;
  }

  post_k<<<dim3(Bn), dim3(Tn), 0, stream>>>(ddot, fc_b, npred, out);
}